// Round 1
// baseline (662.681 us; speedup 1.0000x reference)
//
#include <hip/hip_runtime.h>
#include <hip/hip_bf16.h>
#include <cstdint>
#include <cstddef>

// Problem constants (fixed by the reference setup)
#define NE 8
#define NT 16384
#define ND 2048
#define NH 1024

typedef __bf16 bf16;
typedef __bf16 bf16x8 __attribute__((ext_vector_type(8)));
typedef float f32x4 __attribute__((ext_vector_type(4)));

// Address-space casts for global_load_lds. Generic->AS1 is a no-op on amdgcn;
// generic->AS3 truncates to the 32-bit LDS offset (shared aperture is 4GB-aligned).
#define AS1(p) ((__attribute__((address_space(1))) void*)(uintptr_t)(p))
#define AS3(p) ((__attribute__((address_space(3))) void*)(uint32_t)(uintptr_t)(p))
// 16B-wide async global->LDS (global_load_lds_dwordx4). HW writes wave-uniform
// base + lane*16, so per-wave LDS destinations must be exactly contiguous.
#define GLDS16(g, l) __builtin_amdgcn_global_load_lds(AS1(g), AS3(l), 16, 0, 0)

__device__ __forceinline__ int expert_of_row(const int* __restrict__ counts, int row0) {
  int e = 0, cum = 0;
#pragma unroll
  for (int i = 0; i < NE; ++i) {
    if (row0 >= cum) e = i;
    cum += counts[i];
  }
  return e;
}

// ---------------- f32 -> bf16 conversion (memory-bound, 8 elem/thread) -------
__global__ void cvt_kernel(const float* __restrict__ src, bf16* __restrict__ dst, int n8) {
  int i = blockIdx.x * blockDim.x + threadIdx.x;
  if (i >= n8) return;
  const f32x4* s = (const f32x4*)src + (size_t)i * 2;
  f32x4 a = s[0];
  f32x4 b = s[1];
  bf16x8 o;
  o[0] = (bf16)a[0]; o[1] = (bf16)a[1]; o[2] = (bf16)a[2]; o[3] = (bf16)a[3];
  o[4] = (bf16)b[0]; o[5] = (bf16)b[1]; o[6] = (bf16)b[2]; o[7] = (bf16)b[3];
  *((bf16x8*)dst + i) = o;
}

// ---------------- GEMM1: h = silu(x @ w1^T) * (x @ w3^T), bf16 out -----------
// Tile: BM=128, BN=64, BK=32. 256 thr = 4 waves in a 2x2 grid; each wave owns a
// 64x32 sub-tile = 4x2 MFMA tiles, with TWO accumulator sets (w1 and w3).
__global__ __launch_bounds__(256) void gemm1_kernel(
    const bf16* __restrict__ X, const bf16* __restrict__ W1,
    const bf16* __restrict__ W3, const int* __restrict__ counts,
    bf16* __restrict__ Hb) {
  const int cb = blockIdx.x;   // H/64  = 16
  const int rb = blockIdx.y;   // T/128 = 128
  const int t = threadIdx.x;
  const int lane = t & 63;
  const int wave = t >> 6;
  const int wr = wave >> 1;    // wave row 0..1 (64 rows each)
  const int wc = wave & 1;     // wave col 0..1 (32 cols each)
  const int l16 = lane & 15;
  const int kq = lane >> 4;    // 0..3

  const int row0 = rb * 128;
  const int e = expert_of_row(counts, row0);

  const bf16* Xe  = X  + (size_t)row0 * ND;
  const bf16* W1e = W1 + (size_t)e * NH * ND + (size_t)cb * 64 * ND;
  const bf16* W3e = W3 + (size_t)e * NH * ND + (size_t)cb * 64 * ND;

  __shared__ __align__(16) bf16 As[128 * 32];   // 8 KB, row-major [128][32], no pad
  __shared__ __align__(16) bf16 B1s[64 * 32];   // 4 KB
  __shared__ __align__(16) bf16 B3s[64 * 32];   // 4 KB

  const int srow = t >> 2;         // 0..63
  const int scol = (t & 3) * 8;    // 0,8,16,24 (bf16 elems)

  f32x4 acc1[4][2] = {};
  f32x4 acc3[4][2] = {};

  for (int ko = 0; ko < ND; ko += 32) {
    // Stage: A is 2 rounds of 4 KB, B1/B3 one round each. LDS dst = t*16 bytes.
    GLDS16(Xe  + (size_t)srow * ND + ko + scol,        As + t * 8);
    GLDS16(Xe  + (size_t)(srow + 64) * ND + ko + scol, As + 2048 + t * 8);
    GLDS16(W1e + (size_t)srow * ND + ko + scol,        B1s + t * 8);
    GLDS16(W3e + (size_t)srow * ND + ko + scol,        B3s + t * 8);
    __syncthreads();

    bf16x8 a[4], b1[2], b3[2];
#pragma unroll
    for (int i = 0; i < 4; ++i)
      a[i] = *(const bf16x8*)(As + (wr * 64 + i * 16 + l16) * 32 + kq * 8);
#pragma unroll
    for (int j = 0; j < 2; ++j) {
      b1[j] = *(const bf16x8*)(B1s + (wc * 32 + j * 16 + l16) * 32 + kq * 8);
      b3[j] = *(const bf16x8*)(B3s + (wc * 32 + j * 16 + l16) * 32 + kq * 8);
    }
#pragma unroll
    for (int i = 0; i < 4; ++i)
#pragma unroll
      for (int j = 0; j < 2; ++j) {
        acc1[i][j] = __builtin_amdgcn_mfma_f32_16x16x32_bf16(a[i], b1[j], acc1[i][j], 0, 0, 0);
        acc3[i][j] = __builtin_amdgcn_mfma_f32_16x16x32_bf16(a[i], b3[j], acc3[i][j], 0, 0, 0);
      }
    __syncthreads();
  }

  // Epilogue: C/D layout col=lane&15, row=(lane>>4)*4+reg. silu(a1)*a3 -> bf16.
  const int rbase = row0 + wr * 64 + kq * 4;
  const int cbase = cb * 64 + wc * 32 + l16;
#pragma unroll
  for (int i = 0; i < 4; ++i)
#pragma unroll
    for (int j = 0; j < 2; ++j) {
      const int col = cbase + j * 16;
#pragma unroll
      for (int r = 0; r < 4; ++r) {
        const int row = rbase + i * 16 + r;
        const float v1 = acc1[i][j][r];
        const float v3 = acc3[i][j][r];
        const float hv = (v1 / (1.0f + __expf(-v1))) * v3;
        Hb[(size_t)row * NH + col] = (bf16)hv;
      }
    }
}

// ---------------- GEMM2: out = h @ w2^T, f32 out ------------------------------
// Tile: BM=128, BN=128, BK=32. 4 waves 2x2; each wave 64x64 = 4x4 MFMA tiles.
__global__ __launch_bounds__(256) void gemm2_kernel(
    const bf16* __restrict__ Hb, const bf16* __restrict__ W2,
    const int* __restrict__ counts, float* __restrict__ Out) {
  const int cb = blockIdx.x;   // D/128 = 16
  const int rb = blockIdx.y;   // T/128 = 128
  const int t = threadIdx.x;
  const int lane = t & 63;
  const int wave = t >> 6;
  const int wr = wave >> 1;
  const int wc = wave & 1;
  const int l16 = lane & 15;
  const int kq = lane >> 4;

  const int row0 = rb * 128;
  const int e = expert_of_row(counts, row0);

  const bf16* He  = Hb + (size_t)row0 * NH;
  const bf16* W2e = W2 + (size_t)e * ND * NH + (size_t)cb * 128 * NH;

  __shared__ __align__(16) bf16 As[128 * 32];   // 8 KB
  __shared__ __align__(16) bf16 Bs[128 * 32];   // 8 KB

  const int srow = t >> 2;
  const int scol = (t & 3) * 8;

  f32x4 acc[4][4] = {};

  for (int ko = 0; ko < NH; ko += 32) {
    GLDS16(He  + (size_t)srow * NH + ko + scol,        As + t * 8);
    GLDS16(He  + (size_t)(srow + 64) * NH + ko + scol, As + 2048 + t * 8);
    GLDS16(W2e + (size_t)srow * NH + ko + scol,        Bs + t * 8);
    GLDS16(W2e + (size_t)(srow + 64) * NH + ko + scol, Bs + 2048 + t * 8);
    __syncthreads();

    bf16x8 a[4], b[4];
#pragma unroll
    for (int i = 0; i < 4; ++i)
      a[i] = *(const bf16x8*)(As + (wr * 64 + i * 16 + l16) * 32 + kq * 8);
#pragma unroll
    for (int j = 0; j < 4; ++j)
      b[j] = *(const bf16x8*)(Bs + (wc * 64 + j * 16 + l16) * 32 + kq * 8);
#pragma unroll
    for (int i = 0; i < 4; ++i)
#pragma unroll
      for (int j = 0; j < 4; ++j)
        acc[i][j] = __builtin_amdgcn_mfma_f32_16x16x32_bf16(a[i], b[j], acc[i][j], 0, 0, 0);
    __syncthreads();
  }

  const int rbase = row0 + wr * 64 + kq * 4;
  const int cbase = cb * 128 + wc * 64 + l16;
#pragma unroll
  for (int i = 0; i < 4; ++i)
#pragma unroll
    for (int j = 0; j < 4; ++j) {
      const int col = cbase + j * 16;
#pragma unroll
      for (int r = 0; r < 4; ++r) {
        const int row = rbase + i * 16 + r;
        Out[(size_t)row * ND + col] = acc[i][j][r];
      }
    }
}

// -----------------------------------------------------------------------------
extern "C" void kernel_launch(void* const* d_in, const int* in_sizes, int n_in,
                              void* d_out, int out_size, void* d_ws, size_t ws_size,
                              hipStream_t stream) {
  const float* x     = (const float*)d_in[0];
  const int* counts  = (const int*)d_in[1];
  const float* w1    = (const float*)d_in[2];
  const float* w2    = (const float*)d_in[3];
  const float* w3    = (const float*)d_in[4];
  float* out = (float*)d_out;

  char* ws = (char*)d_ws;
  const size_t xN = (size_t)NT * ND;       // 33.5M elems
  const size_t wN = (size_t)NE * NH * ND;  // 16.8M elems per weight
  bf16* xb  = (bf16*)ws;                                  //  64 MiB
  bf16* w1b = (bf16*)(ws + xN * 2);                       // +32 MiB
  bf16* w3b = (bf16*)(ws + xN * 2 + wN * 2);              // +32 MiB
  bf16* w2b = (bf16*)(ws + xN * 2 + 2 * wN * 2);          // +32 MiB
  bf16* hb  = (bf16*)(ws + xN * 2 + 3 * wN * 2);          // +32 MiB (h: T x H bf16)

  { int n8 = (int)(xN / 8); cvt_kernel<<<dim3((n8 + 255) / 256), dim3(256), 0, stream>>>(x, xb, n8); }
  { int n8 = (int)(wN / 8); cvt_kernel<<<dim3((n8 + 255) / 256), dim3(256), 0, stream>>>(w1, w1b, n8); }
  { int n8 = (int)(wN / 8); cvt_kernel<<<dim3((n8 + 255) / 256), dim3(256), 0, stream>>>(w3, w3b, n8); }
  { int n8 = (int)(wN / 8); cvt_kernel<<<dim3((n8 + 255) / 256), dim3(256), 0, stream>>>(w2, w2b, n8); }

  gemm1_kernel<<<dim3(NH / 64, NT / 128), dim3(256), 0, stream>>>(xb, w1b, w3b, counts, hb);
  gemm2_kernel<<<dim3(ND / 128, NT / 128), dim3(256), 0, stream>>>(hb, w2b, counts, out);
}

// Round 2
// 653.066 us; speedup vs baseline: 1.0147x; 1.0147x over previous
//
#include <hip/hip_runtime.h>
#include <hip/hip_bf16.h>
#include <cstdint>
#include <cstddef>

// Problem constants (fixed by the reference setup)
#define NE 8
#define NT 16384
#define ND 2048
#define NH 1024

typedef __bf16 bf16;
typedef __bf16 bf16x8 __attribute__((ext_vector_type(8)));
typedef float f32x4 __attribute__((ext_vector_type(4)));

// Address-space casts for global_load_lds. Generic->AS1 is a no-op on amdgcn;
// generic->AS3 truncates to the 32-bit LDS offset.
#define AS1(p) ((__attribute__((address_space(1))) void*)(uintptr_t)(p))
#define AS3(p) ((__attribute__((address_space(3))) void*)(uint32_t)(uintptr_t)(p))
// 16B-wide async global->LDS (global_load_lds_dwordx4). HW writes wave-uniform
// base + lane*16, so per-wave LDS destinations must be exactly contiguous.
#define GLDS16(g, l) __builtin_amdgcn_global_load_lds(AS1(g), AS3(l), 16, 0, 0)

// LDS XOR swizzle: physical 16B-slot p of row r holds logical col-block
// g = p ^ ((r>>1)&3).  Staging: thread t -> (r=t>>2, p=t&3) loads global
// col-block (t&3)^((t>>3)&3).  Reads: logical block kq lives at physical slot
// kq ^ ((row>>1)&3); for MFMA reads row = <mult of 8> + l16, so the xor term
// is (l16>>1)&3 -- loop-invariant per lane.  Result: 16 lanes of a ds_read_b128
// spread over all 8 bank-quads exactly twice (2-way = free, m136), vs 8-way
// conflict unswizzled (was 1.7e7 SQ_LDS_BANK_CONFLICT/dispatch).

__device__ __forceinline__ int expert_of_row(const int* __restrict__ counts, int row0) {
  int e = 0, cum = 0;
#pragma unroll
  for (int i = 0; i < NE; ++i) {
    if (row0 >= cum) e = i;
    cum += counts[i];
  }
  return e;
}

// ---------------- f32 -> bf16 conversion (memory-bound, 8 elem/thread) -------
__global__ void cvt_kernel(const float* __restrict__ src, bf16* __restrict__ dst, int n8) {
  int i = blockIdx.x * blockDim.x + threadIdx.x;
  if (i >= n8) return;
  const f32x4* s = (const f32x4*)src + (size_t)i * 2;
  f32x4 a = s[0];
  f32x4 b = s[1];
  bf16x8 o;
  o[0] = (bf16)a[0]; o[1] = (bf16)a[1]; o[2] = (bf16)a[2]; o[3] = (bf16)a[3];
  o[4] = (bf16)b[0]; o[5] = (bf16)b[1]; o[6] = (bf16)b[2]; o[7] = (bf16)b[3];
  *((bf16x8*)dst + i) = o;
}

// ---------------- GEMM1: h = silu(x @ w1^T) * (x @ w3^T), bf16 out -----------
// Tile: BM=128, BN=64(dual), BK=32. 256 thr = 4 waves 2x2; each wave owns a
// 64x32 sub-tile = 4x2 MFMA tiles, with TWO accumulator sets (w1 and w3).
__global__ __launch_bounds__(256) void gemm1_kernel(
    const bf16* __restrict__ X, const bf16* __restrict__ W1,
    const bf16* __restrict__ W3, const int* __restrict__ counts,
    bf16* __restrict__ Hb) {
  const int cb = blockIdx.x;   // H/64  = 16
  const int rb = blockIdx.y;   // T/128 = 128
  const int t = threadIdx.x;
  const int lane = t & 63;
  const int wave = t >> 6;
  const int wr = wave >> 1;    // wave row 0..1 (64 rows each)
  const int wc = wave & 1;     // wave col 0..1 (32 cols each)
  const int l16 = lane & 15;
  const int kq = lane >> 4;    // 0..3
  const int kqs = kq ^ ((l16 >> 1) & 3);   // swizzled physical slot for reads

  const int row0 = rb * 128;
  const int e = expert_of_row(counts, row0);

  const bf16* Xe  = X  + (size_t)row0 * ND;
  const bf16* W1e = W1 + (size_t)e * NH * ND + (size_t)cb * 64 * ND;
  const bf16* W3e = W3 + (size_t)e * NH * ND + (size_t)cb * 64 * ND;

  __shared__ __align__(16) bf16 As[128 * 32];   // 8 KB, [128][4 slots of 8]
  __shared__ __align__(16) bf16 B1s[64 * 32];   // 4 KB
  __shared__ __align__(16) bf16 B3s[64 * 32];   // 4 KB

  const int srow = t >> 2;                          // 0..63
  const int scol = (((t & 3) ^ ((t >> 3) & 3)) * 8);  // swizzled global col-block

  f32x4 acc1[4][2] = {};
  f32x4 acc3[4][2] = {};

  for (int ko = 0; ko < ND; ko += 32) {
    // Stage: A is 2 rounds of 4 KB, B1/B3 one round each. LDS dst = t*16 bytes.
    // ((srow+64)>>1)&3 == (srow>>1)&3, so the same swizzled scol serves both.
    GLDS16(Xe  + (size_t)srow * ND + ko + scol,        As + t * 8);
    GLDS16(Xe  + (size_t)(srow + 64) * ND + ko + scol, As + 2048 + t * 8);
    GLDS16(W1e + (size_t)srow * ND + ko + scol,        B1s + t * 8);
    GLDS16(W3e + (size_t)srow * ND + ko + scol,        B3s + t * 8);
    __syncthreads();

    bf16x8 a[4], b1[2], b3[2];
#pragma unroll
    for (int i = 0; i < 4; ++i)
      a[i] = *(const bf16x8*)(As + (wr * 64 + i * 16 + l16) * 32 + kqs * 8);
#pragma unroll
    for (int j = 0; j < 2; ++j) {
      b1[j] = *(const bf16x8*)(B1s + (wc * 32 + j * 16 + l16) * 32 + kqs * 8);
      b3[j] = *(const bf16x8*)(B3s + (wc * 32 + j * 16 + l16) * 32 + kqs * 8);
    }
#pragma unroll
    for (int i = 0; i < 4; ++i)
#pragma unroll
      for (int j = 0; j < 2; ++j) {
        acc1[i][j] = __builtin_amdgcn_mfma_f32_16x16x32_bf16(a[i], b1[j], acc1[i][j], 0, 0, 0);
        acc3[i][j] = __builtin_amdgcn_mfma_f32_16x16x32_bf16(a[i], b3[j], acc3[i][j], 0, 0, 0);
      }
    __syncthreads();
  }

  // Epilogue: C/D layout col=lane&15, row=(lane>>4)*4+reg. silu(a1)*a3 -> bf16.
  const int rbase = row0 + wr * 64 + kq * 4;
  const int cbase = cb * 64 + wc * 32 + l16;
#pragma unroll
  for (int i = 0; i < 4; ++i)
#pragma unroll
    for (int j = 0; j < 2; ++j) {
      const int col = cbase + j * 16;
#pragma unroll
      for (int r = 0; r < 4; ++r) {
        const int row = rbase + i * 16 + r;
        const float v1 = acc1[i][j][r];
        const float v3 = acc3[i][j][r];
        const float hv = (v1 / (1.0f + __expf(-v1))) * v3;
        Hb[(size_t)row * NH + col] = (bf16)hv;
      }
    }
}

// ---------------- GEMM2: out = h @ w2^T, f32 out ------------------------------
// Tile: BM=128, BN=128, BK=32. 4 waves 2x2; each wave 64x64 = 4x4 MFMA tiles.
__global__ __launch_bounds__(256) void gemm2_kernel(
    const bf16* __restrict__ Hb, const bf16* __restrict__ W2,
    const int* __restrict__ counts, float* __restrict__ Out) {
  const int cb = blockIdx.x;   // D/128 = 16
  const int rb = blockIdx.y;   // T/128 = 128
  const int t = threadIdx.x;
  const int lane = t & 63;
  const int wave = t >> 6;
  const int wr = wave >> 1;
  const int wc = wave & 1;
  const int l16 = lane & 15;
  const int kq = lane >> 4;
  const int kqs = kq ^ ((l16 >> 1) & 3);

  const int row0 = rb * 128;
  const int e = expert_of_row(counts, row0);

  const bf16* He  = Hb + (size_t)row0 * NH;
  const bf16* W2e = W2 + (size_t)e * ND * NH + (size_t)cb * 128 * NH;

  __shared__ __align__(16) bf16 As[128 * 32];   // 8 KB
  __shared__ __align__(16) bf16 Bs[128 * 32];   // 8 KB

  const int srow = t >> 2;
  const int scol = (((t & 3) ^ ((t >> 3) & 3)) * 8);

  f32x4 acc[4][4] = {};

  for (int ko = 0; ko < NH; ko += 32) {
    GLDS16(He  + (size_t)srow * NH + ko + scol,        As + t * 8);
    GLDS16(He  + (size_t)(srow + 64) * NH + ko + scol, As + 2048 + t * 8);
    GLDS16(W2e + (size_t)srow * NH + ko + scol,        Bs + t * 8);
    GLDS16(W2e + (size_t)(srow + 64) * NH + ko + scol, Bs + 2048 + t * 8);
    __syncthreads();

    bf16x8 a[4], b[4];
#pragma unroll
    for (int i = 0; i < 4; ++i)
      a[i] = *(const bf16x8*)(As + (wr * 64 + i * 16 + l16) * 32 + kqs * 8);
#pragma unroll
    for (int j = 0; j < 4; ++j)
      b[j] = *(const bf16x8*)(Bs + (wc * 64 + j * 16 + l16) * 32 + kqs * 8);
#pragma unroll
    for (int i = 0; i < 4; ++i)
#pragma unroll
      for (int j = 0; j < 4; ++j)
        acc[i][j] = __builtin_amdgcn_mfma_f32_16x16x32_bf16(a[i], b[j], acc[i][j], 0, 0, 0);
    __syncthreads();
  }

  const int rbase = row0 + wr * 64 + kq * 4;
  const int cbase = cb * 128 + wc * 64 + l16;
#pragma unroll
  for (int i = 0; i < 4; ++i)
#pragma unroll
    for (int j = 0; j < 4; ++j) {
      const int col = cbase + j * 16;
#pragma unroll
      for (int r = 0; r < 4; ++r) {
        const int row = rbase + i * 16 + r;
        Out[(size_t)row * ND + col] = acc[i][j][r];
      }
    }
}

// -----------------------------------------------------------------------------
extern "C" void kernel_launch(void* const* d_in, const int* in_sizes, int n_in,
                              void* d_out, int out_size, void* d_ws, size_t ws_size,
                              hipStream_t stream) {
  const float* x     = (const float*)d_in[0];
  const int* counts  = (const int*)d_in[1];
  const float* w1    = (const float*)d_in[2];
  const float* w2    = (const float*)d_in[3];
  const float* w3    = (const float*)d_in[4];
  float* out = (float*)d_out;

  char* ws = (char*)d_ws;
  const size_t xN = (size_t)NT * ND;       // 33.5M elems
  const size_t wN = (size_t)NE * NH * ND;  // 16.8M elems per weight
  bf16* xb  = (bf16*)ws;                                  //  64 MiB
  bf16* w1b = (bf16*)(ws + xN * 2);                       // +32 MiB
  bf16* w3b = (bf16*)(ws + xN * 2 + wN * 2);              // +32 MiB
  bf16* w2b = (bf16*)(ws + xN * 2 + 2 * wN * 2);          // +32 MiB
  bf16* hb  = (bf16*)(ws + xN * 2 + 3 * wN * 2);          // +32 MiB (h: T x H bf16)

  { int n8 = (int)(xN / 8); cvt_kernel<<<dim3((n8 + 255) / 256), dim3(256), 0, stream>>>(x, xb, n8); }
  { int n8 = (int)(wN / 8); cvt_kernel<<<dim3((n8 + 255) / 256), dim3(256), 0, stream>>>(w1, w1b, n8); }
  { int n8 = (int)(wN / 8); cvt_kernel<<<dim3((n8 + 255) / 256), dim3(256), 0, stream>>>(w3, w3b, n8); }
  { int n8 = (int)(wN / 8); cvt_kernel<<<dim3((n8 + 255) / 256), dim3(256), 0, stream>>>(w2, w2b, n8); }

  gemm1_kernel<<<dim3(NH / 64, NT / 128), dim3(256), 0, stream>>>(xb, w1b, w3b, counts, hb);
  gemm2_kernel<<<dim3(ND / 128, NT / 128), dim3(256), 0, stream>>>(hb, w2b, counts, out);
}